// Round 10
// baseline (691.506 us; speedup 1.0000x reference)
//
#include <hip/hip_runtime.h>
#include <hip/hip_bf16.h>
#include <math.h>

typedef __attribute__((ext_vector_type(8))) short bf16x8;
typedef __attribute__((ext_vector_type(4))) float f32x4;
typedef __attribute__((ext_vector_type(4))) unsigned u32x4;
typedef __attribute__((ext_vector_type(2))) float f32x2;
typedef __attribute__((ext_vector_type(2))) unsigned u32x2;

#define C_NLOG2E -1.4426950408889634f
#define C_NLN2   -0.6931471805599453f

__device__ __forceinline__ float silu_f(float x){
  return x * __builtin_amdgcn_rcpf(1.f + __expf(-x));
}

// scaled-domain silu accumulate, PAIRED, one trans op (exp2) per value:
// h = -log2e*x; s += h * sigma(x) with sigma = 1/(1+2^h) via integer-magic
// reciprocal + 2 Newton steps (rel err ~7e-6, far below bf16). h clamped at 30
// so exp2 can't reach inf (magic-sub on inf would NaN); sigma(30)~1e-9 -> 0.
// float2 form lets clang emit v_pk_{add,mul,fma}_f32 for the full-rate part.
__device__ __forceinline__ void silu2(float h0, float h1, f32x2& s){
  f32x2 h; h.x = fminf(h0, 30.f); h.y = fminf(h1, 30.f);
  f32x2 e; e.x = __builtin_amdgcn_exp2f(h.x); e.y = __builtin_amdgcn_exp2f(h.y);
  f32x2 d = e + 1.f;
  u32x2 di = __builtin_bit_cast(u32x2, d);
  u32x2 ri; ri.x = 0x7EF311C3u - di.x; ri.y = 0x7EF311C3u - di.y;
  f32x2 r = __builtin_bit_cast(f32x2, ri);
  r = r * (2.f - d*r);
  r = r * (2.f - d*r);
  s += h * r;
}

// fp32 -> bf16 (round-to-nearest-even, finite inputs)
__device__ __forceinline__ short f2bs(float x){
  unsigned u = __builtin_bit_cast(unsigned, x);
  unsigned r = (u + 0x7fffu + ((u >> 16) & 1u)) >> 16;
  return (short)r;
}
__device__ __forceinline__ float bs2f(ushort u){
  unsigned v = ((unsigned)u) << 16;
  return __builtin_bit_cast(float, v);
}

// pack 2 fp32 -> 2 bf16 in one u32 (RNE), 1 instr; low = first arg
__device__ __forceinline__ unsigned pk2(float a, float b){
  unsigned r;
  asm("v_cvt_pk_bf16_f32 %0, %1, %2" : "=v"(r) : "v"(a), "v"(b));
  return r;
}

// K-permutation for A's hidden dim ONLY (lane-major layout of k_edge3's output):
// A position p holds logical hidden col ((p&7)*16 + (p>>3)); p_ew2 rows permuted to match.
__device__ __forceinline__ int kperm(int k){ return ((k & 7) << 4) | (k >> 3); }

// ---------------- edge-index layout detect (int64 vs int32) ----------------
__global__ void k_detect(const int* __restrict__ ei, int E, int* __restrict__ flag){
  __shared__ int nz;
  if (threadIdx.x==0) nz = 0;
  __syncthreads();
  int lim = E < 4096 ? E : 4096;
  int c = 0;
  for (int e = threadIdx.x; e < lim; e += blockDim.x)
    if (ei[2*e+1] != 0) c++;
  if (c) atomicAdd(&nz, c);
  __syncthreads();
  if (threadIdx.x==0) *flag = (nz==0) ? 1 : 0;   // 1 => int64 little-endian
}

__global__ __launch_bounds__(256) void k_deg(const int* __restrict__ ei, int E,
                                             const int* __restrict__ flag, int* __restrict__ deg){
  int e = blockIdx.x*blockDim.x + threadIdx.x;
  if (e >= E) return;
  int d = (*flag) ? ei[2*(E+e)] : ei[E+e];
  atomicAdd(&deg[d], 1);
}

// ---------------- scan stage 1 + fused per-node precompute ----------------
__global__ __launch_bounds__(256) void k_scan1(const int* __restrict__ deg, int* __restrict__ offs,
                                               int* __restrict__ bsum,
                                               const float* __restrict__ x, float4* __restrict__ nrec,
                                               int n){
  __shared__ int sh[256];
  int i = blockIdx.x*256 + threadIdx.x;
  int v = (i < n) ? deg[i] : 0;
  sh[threadIdx.x] = v;
  if (i < n){
    float nt0 = x[i*5+0], nt1 = x[i*5+1];
    float sx = x[i*5+2], sy = x[i*5+3], sz = x[i*5+4];
    float nrm = sqrtf(sx*sx + sy*sy + sz*sz);
    float d = fmaxf(nrm, 1e-12f);
    float mx = sx/d, my = sy/d, mz = sz/d;
    float rn = sqrtf(mx*mx + my*my + mz*mz);
    nrec[(size_t)i*2]   = make_float4(mx, my, mz, rn);
    nrec[(size_t)i*2+1] = make_float4(nt0, nt1, 0.f, 0.f);
  }
  __syncthreads();
  for (int off=1; off<256; off<<=1){
    int t = (threadIdx.x >= off) ? sh[threadIdx.x-off] : 0;
    __syncthreads();
    sh[threadIdx.x] += t;
    __syncthreads();
  }
  if (i < n) offs[i] = sh[threadIdx.x] - v;
  if (threadIdx.x == 255) bsum[blockIdx.x] = sh[255];
}

__global__ __launch_bounds__(512) void k_scan2(int* __restrict__ bsum, int nb){
  __shared__ int sh[512];
  int v = (threadIdx.x < nb) ? bsum[threadIdx.x] : 0;
  sh[threadIdx.x] = v;
  __syncthreads();
  for (int off=1; off<512; off<<=1){
    int t = (threadIdx.x >= off) ? sh[threadIdx.x-off] : 0;
    __syncthreads();
    sh[threadIdx.x] += t;
    __syncthreads();
  }
  if (threadIdx.x < nb) bsum[threadIdx.x] = sh[threadIdx.x] - v;
}

// ---------------- scan stage 3 + fused remainder-worklist build ----------------
__global__ __launch_bounds__(256) void k_scan3(int* __restrict__ offs, const int* __restrict__ bsum,
                                               int* __restrict__ cursor,
                                               const int* __restrict__ deg,
                                               int* __restrict__ cnt, int4* __restrict__ c4,
                                               int4* __restrict__ c8, int n){
  int i = blockIdx.x*256 + threadIdx.x;
  if (i >= n) return;
  int o = offs[i] + bsum[i>>8];
  offs[i] = o;
  cursor[i] = o;
  int d = deg[i];
  int r = d & 15;
  if (r == 0 || r >= 9) return;
  int base = o + (d & ~15);
  if (r <= 4){
    int s = atomicAdd(&cnt[0], 1);
    c4[s] = make_int4(i, base, r, 0);
  } else {
    int s = atomicAdd(&cnt[1], 2);         // pair-aligned: node owns quads (q, q+1)
    c8[s]   = make_int4(i, base, 4, 0);
    c8[s+1] = make_int4(i, base+4, r-4, 0);
  }
}

// ---------------- scatter edges into dst-sorted order (32 B bf16 rows) ----------------
// scE row (16 bf16): [|m_i|,|m_j|,mi·mj,mi·u,mj·u,dist,nti0,nti1,ntj0,ntj1, 1.0, 0...]
// Row packed via pk2 (5 instrs instead of ~40).
__global__ __launch_bounds__(256) void k_scatter(const int* __restrict__ ei, int E,
                                                 const int* __restrict__ flag,
                                                 const float* __restrict__ eattr,
                                                 const float4* __restrict__ nrec,
                                                 int* __restrict__ cursor,
                                                 int* __restrict__ srcS, ushort* __restrict__ scE){
  int e = blockIdx.x*blockDim.x + threadIdx.x;
  if (e >= E) return;
  int i64 = *flag;
  int s = i64 ? ei[2*e]       : ei[e];
  int d = i64 ? ei[2*(E+e)]   : ei[E+e];
  float4 ea = *(const float4*)(eattr + (size_t)e*4);
  float4 mi  = nrec[(size_t)d*2];
  float4 nti = nrec[(size_t)d*2+1];
  float4 mj  = nrec[(size_t)s*2];
  float4 ntj = nrec[(size_t)s*2+1];
  u32x4 q0, q1;
  q0[0] = pk2(mi.w, mj.w);
  q0[1] = pk2(mi.x*mj.x + mi.y*mj.y + mi.z*mj.z,
              mi.x*ea.x + mi.y*ea.y + mi.z*ea.z);
  q0[2] = pk2(mj.x*ea.x + mj.y*ea.y + mj.z*ea.z, ea.w);
  q0[3] = pk2(nti.x, nti.y);
  q1[0] = pk2(ntj.x, ntj.y);
  q1[1] = 0x3F80u;   // bf16 1.0 in low slot (bias row), high slot 0
  q1[2] = 0u;
  q1[3] = 0u;
  int pos = atomicAdd(&cursor[d], 1);
  srcS[pos] = s;
  u32x4* dstp = (u32x4*)(scE + (size_t)pos*16);
  dstp[0] = q0;
  dstp[1] = q1;
}

// ---------------- pack weights to MFMA B-fragment-major bf16 ----------------
// p_ew1 scaled by -log2e (incl. bias row). p_ew2 scaled by -ln2 (undoes A's scale)
// AND K-row-permuted by kperm (matches A's lane-major layout). nw1/nw2/ow1 standard.
__global__ __launch_bounds__(64) void k_pack(const float* __restrict__ ew2, const float* __restrict__ nw1,
                                             const float* __restrict__ nw2, const float* __restrict__ ow1,
                                             const float* __restrict__ ew1, const float* __restrict__ eb1,
                                             short* __restrict__ p_ew2, short* __restrict__ p_nw1,
                                             short* __restrict__ p_nw2, short* __restrict__ p_ow1,
                                             short* __restrict__ p_ew1){
  int b = blockIdx.x;
  int L = threadIdx.x;
  if (b >= 416){
    int tile = b - 416;          // 0..23
    int l = tile >> 3, t = tile & 7;
    int col = t*16 + (L & 15);
    int kb  = (L >> 4) << 3;
    __align__(16) short tmp[8];
    #pragma unroll
    for (int e=0;e<8;e++){
      int k = kb + e;
      float v = 0.f;
      if (k < 10)       v = ew1[(size_t)l*1280 + (size_t)k*128 + col];
      else if (k == 10) v = eb1[(size_t)l*128 + col];
      tmp[e] = f2bs(v * C_NLOG2E);
    }
    *(bf16x8*)(p_ew1 + (size_t)l*4096 + t*512 + L*8) = *(bf16x8*)tmp;
    return;
  }
  const float* src; short* dst; int tile;
  float sc = 1.f;
  bool perm = false;
  if (b < 96){        int l = b>>5;              tile = b & 31; src = ew2 + (size_t)l*16384; dst = p_ew2 + (size_t)l*16384; sc = C_NLN2; perm = true; }
  else if (b < 288){  int l = (b-96)>>6;         tile = (b-96) & 63; src = nw1 + (size_t)l*32768; dst = p_nw1 + (size_t)l*32768; }
  else if (b < 384){  int l = (b-288)>>5;        tile = (b-288) & 31; src = nw2 + (size_t)l*16384; dst = p_nw2 + (size_t)l*16384; }
  else {                                          tile = b - 384; src = ow1; dst = p_ow1; }
  int c = tile >> 3, t = tile & 7;
  int kb  = c*32 + ((L>>4)<<3);
  int col = t*16 + (L&15);
  __align__(16) short tmp[8];
  #pragma unroll
  for (int e=0;e<8;e++){
    int k = kb + e;
    int kk = perm ? kperm(k) : k;
    tmp[e] = f2bs(src[(size_t)kk*128 + col] * sc);
  }
  *(bf16x8*)(dst + ((size_t)tile*64 + L)*8) = *(bf16x8*)tmp;
}

// ---------------- edge MLP hidden sums: full 16-groups (+ tails>=9), wave per node ----------------
// A written lane-major: lane lr's 8 sums -> 4 cvt_pk + ONE b128 store.
// silu: one trans op per value (exp2 + magic-rcp), float2-packed accumulators.
__global__ __launch_bounds__(256) void k_edge3(
    const ushort* __restrict__ scE,
    const int* __restrict__ offs, const int* __restrict__ deg,
    const short* __restrict__ p_ew1,
    ushort* __restrict__ A, int n, size_t lstride){
  int wv = threadIdx.x >> 6, lane = threadIdx.x & 63;
  int i = blockIdx.x*4 + wv;
  if (i >= n) return;
  int quad = lane >> 4, lr = lane & 15;
  int p0 = __builtin_amdgcn_readfirstlane(offs[i]);
  int dg = __builtin_amdgcn_readfirstlane(deg[i]);
  int r  = dg & 15;
  int gfull = dg & ~15;                         // unmasked full groups
  const f32x4 zf = {0.f,0.f,0.f,0.f};
  const u32x4 z4 = {0u,0u,0u,0u};
  #pragma unroll 1
  for (int l=0; l<3; ++l){
    const short* pB = p_ew1 + (size_t)l*4096 + (size_t)lane*8;
    bf16x8 bfr[8];                                // hoist loop-invariant B-fragments
    #pragma unroll
    for (int t=0;t<8;t++) bfr[t] = *(const bf16x8*)(pB + t*512);
    f32x2 s2[8];
    #pragma unroll
    for (int t=0;t<8;t++){ s2[t].x = 0.f; s2[t].y = 0.f; }
    auto body = [&](u32x4 d4){
      bf16x8 af = __builtin_bit_cast(bf16x8, d4);
      #pragma unroll
      for (int t=0;t<8;t++){
        f32x4 acc = __builtin_amdgcn_mfma_f32_16x16x32_bf16(af, bfr[t], zf, 0, 0, 0);
        silu2(acc[0], acc[1], s2[t]);
        silu2(acc[2], acc[3], s2[t]);
      }
    };
    for (int g=0; g<gfull; g+=16){                // no per-edge bounds check
      u32x4 d4 = z4;
      if (quad < 2)
        d4 = *(const u32x4*)(scE + ((size_t)(p0+g+lr))*16 + quad*8);
      body(d4);
    }
    if (r >= 9){                                   // single masked tail group
      int e = gfull + lr;
      u32x4 d4 = z4;
      if (quad < 2 && e < dg)
        d4 = *(const u32x4*)(scE + ((size_t)(p0+e))*16 + quad*8);
      body(d4);
    }
    float s8[8];
    #pragma unroll
    for (int t=0;t<8;t++){
      s8[t] = s2[t].x + s2[t].y;
      s8[t] += __shfl_xor(s8[t], 16, 64);
      s8[t] += __shfl_xor(s8[t], 32, 64);
    }
    if (quad == 0){
      u32x4 q;
      q[0] = pk2(s8[0], s8[1]);
      q[1] = pk2(s8[2], s8[3]);
      q[2] = pk2(s8[4], s8[5]);
      q[3] = pk2(s8[6], s8[7]);
      *(u32x4*)(A + lstride*l + (size_t)i*128 + lr*8) = q;
    }
  }
}

// ---------------- remainder tiles: 4 nodes/tile (mode 0) or 2 nodes/tile (mode 1) ----------------
__global__ __launch_bounds__(256) void k_edge_rem(
    const ushort* __restrict__ scE,
    const int* __restrict__ cnt,
    const int4* __restrict__ c4, const int4* __restrict__ c8,
    const short* __restrict__ p_ew1,
    ushort* __restrict__ A, size_t lstride, int T4){
  int wave = threadIdx.x >> 6, lane = threadIdx.x & 63;
  int tw = blockIdx.x*4 + wave;
  const int4* slots;
  int mode;
  if (tw < T4){
    if (tw*4 >= cnt[0]) return;             // fully-dummy tile (lists are dense)
    slots = c4 + (size_t)tw*4; mode = 0;
  } else {
    int t2 = tw - T4;
    if (t2*4 >= cnt[1]) return;
    slots = c8 + (size_t)t2*4; mode = 1;
  }
  int lr = lane & 15, quad = lane >> 4;
  int4 sl = slots[lr >> 2];                 // slot for my A-row
  int4 so = slots[quad];                    // slot for my output quad
  u32x4 d4 = {0u,0u,0u,0u};
  if (quad < 2 && (lr & 3) < sl.z)
    d4 = *(const u32x4*)(scE + (size_t)(sl.y + (lr & 3))*16 + quad*8);
  bf16x8 af = __builtin_bit_cast(bf16x8, d4);
  const f32x4 zf = {0.f,0.f,0.f,0.f};
  bool writer = (so.x >= 0) && (mode == 0 || (quad & 1) == 0);
  #pragma unroll 1
  for (int l=0; l<3; ++l){
    const short* pB = p_ew1 + (size_t)l*4096 + (size_t)lane*8;
    float s8[8];
    #pragma unroll
    for (int t=0;t<8;t++){
      bf16x8 bf = *(const bf16x8*)(pB + t*512);
      f32x4 acc = __builtin_amdgcn_mfma_f32_16x16x32_bf16(af, bf, zf, 0, 0, 0);
      f32x2 s; s.x = 0.f; s.y = 0.f;
      silu2(acc[0], acc[1], s);
      silu2(acc[2], acc[3], s);
      s8[t] = s.x + s.y;
    }
    if (mode == 1){
      #pragma unroll
      for (int t=0;t<8;t++) s8[t] += __shfl_xor(s8[t], 16, 64);
    }
    if (writer){
      ushort* Ar = A + lstride*l + (size_t)so.x*128;
      #pragma unroll
      for (int t=0;t<8;t++){
        int p = lr*8 + t;                   // lane-major position of col t*16+lr
        Ar[p] = (ushort)f2bs(bs2f(Ar[p]) + s8[t]);
      }
    }
  }
}

// ---------------- dual-tile MFMA wave GEMM: 2x (16 rows x 128 cols), shared B-frags ----------------
__device__ __forceinline__ void wave_gemm2(const short* __restrict__ s0, const short* __restrict__ s1,
                                           const short* __restrict__ pw, int lane,
                                           f32x4 acc0[8], f32x4 acc1[8]){
  int lro = (lane & 15)*136 + ((lane >> 4) << 3);
  #pragma unroll
  for (int c=0;c<4;c++){
    bf16x8 a0 = *(const bf16x8*)(s0 + lro + c*32);
    bf16x8 a1 = *(const bf16x8*)(s1 + lro + c*32);
    const short* pB = pw + (size_t)c*4096 + (size_t)lane*8;
    #pragma unroll
    for (int t=0;t<8;t++){
      bf16x8 bf = *(const bf16x8*)(pB + t*512);
      acc0[t] = __builtin_amdgcn_mfma_f32_16x16x32_bf16(a0, bf, acc0[t], 0, 0, 0);
      acc1[t] = __builtin_amdgcn_mfma_f32_16x16x32_bf16(a1, bf, acc1[t], 0, 0, 0);
    }
  }
}

// ---------------- ALL 3 node-update layers + head: 1 wave/block, TWO tiles/wave ----------------
// Known-good r7 version: scalar LDS epilogues, standard sH/sG layout.
// GEMM-A reads A lane-major via permuted p_ew2 (product invariant).
__global__ __launch_bounds__(64,2) void k_layers(
    const ushort* __restrict__ A, size_t lstride,
    const short* __restrict__ p_ew2, const float* __restrict__ eb2,
    const short* __restrict__ p_nw1, const float* __restrict__ nb1,
    const short* __restrict__ p_nw2, const float* __restrict__ nb2,
    const int* __restrict__ deg,
    const short* __restrict__ p_ow1, const float* __restrict__ ob1,
    const float* __restrict__ ow2, const float* __restrict__ ob2,
    const float* __restrict__ inw, const float* __restrict__ inb,
    const float4* __restrict__ nrec, float4* __restrict__ wspin, int n){
  __shared__ __align__(16) short sH[2][2176];
  __shared__ __align__(16) short sG[2][2176];
  int lane = threadIdx.x;
  int lr = lane & 15, quad = lane >> 4, qrow = quad << 2;
  int b0 = blockIdx.x*32;           // tile0 rows b0.., tile1 rows b0+16..
  int b1 = b0 + 16;

  const f32x4 zf = {0.f,0.f,0.f,0.f};
  const bf16x8 zb = {0,0,0,0,0,0,0,0};
  f32x4 h0a[8], h1a[8];
  f32x4 acc0[8], acc1[8];
  bool rv0 = (b0 + lr) < n, rv1 = (b1 + lr) < n;
  float dd0[4], dd1[4];

  // ---- h0 = silu([nt0,nt1,|m|] @ in_w + in_b), both tiles ----
  {
    float nt0a[4], nt1a[4], rna[4], nt0b[4], nt1b[4], rnb[4];
    #pragma unroll
    for (int r=0;r<4;r++){
      int ra = b0 + qrow + r, rb = b1 + qrow + r;
      if (ra < n){
        float4 a = nrec[(size_t)ra*2]; float4 b = nrec[(size_t)ra*2+1];
        nt0a[r]=b.x; nt1a[r]=b.y; rna[r]=a.w; dd0[r]=(float)deg[ra];
      } else { nt0a[r]=0.f; nt1a[r]=0.f; rna[r]=0.f; dd0[r]=0.f; }
      if (rb < n){
        float4 a = nrec[(size_t)rb*2]; float4 b = nrec[(size_t)rb*2+1];
        nt0b[r]=b.x; nt1b[r]=b.y; rnb[r]=a.w; dd1[r]=(float)deg[rb];
      } else { nt0b[r]=0.f; nt1b[r]=0.f; rnb[r]=0.f; dd1[r]=0.f; }
    }
    #pragma unroll
    for (int t=0;t<8;t++){
      int col = t*16 + lr;
      float w0=inw[col], w1=inw[128+col], w2=inw[256+col], bb=inb[col];
      #pragma unroll
      for (int r=0;r<4;r++){
        h0a[t][r] = silu_f(nt0a[r]*w0 + nt1a[r]*w1 + rna[r]*w2 + bb);
        h1a[t][r] = silu_f(nt0b[r]*w0 + nt1b[r]*w1 + rnb[r]*w2 + bb);
      }
    }
    #pragma unroll
    for (int t=0;t<8;t++){
      int col = t*16 + lr;
      #pragma unroll
      for (int r=0;r<4;r++){
        sH[0][(qrow+r)*136 + col] = f2bs(h0a[t][r]);
        sH[1][(qrow+r)*136 + col] = f2bs(h1a[t][r]);
      }
    }
  }

  #pragma unroll 1
  for (int l=0;l<3;++l){
    // GEMM-A: aggr = A @ ew2 + deg*eb2 -> sG ; A-frags straight from global, both tiles
    #pragma unroll
    for (int t=0;t<8;t++){ acc0[t] = zf; acc1[t] = zf; }
    {
      const ushort* gA0 = A + lstride*l + ((size_t)(b0 + lr))*128 + qrow*2;  // k-pos = quad*8
      const ushort* gA1 = A + lstride*l + ((size_t)(b1 + lr))*128 + qrow*2;
      const short* pw = p_ew2 + (size_t)l*16384;
      #pragma unroll
      for (int c=0;c<4;c++){
        bf16x8 a0 = rv0 ? *(const bf16x8*)(gA0 + c*32) : zb;
        bf16x8 a1 = rv1 ? *(const bf16x8*)(gA1 + c*32) : zb;
        const short* pB = pw + (size_t)c*4096 + (size_t)lane*8;
        #pragma unroll
        for (int t=0;t<8;t++){
          bf16x8 bf = *(const bf16x8*)(pB + t*512);
          acc0[t] = __builtin_amdgcn_mfma_f32_16x16x32_bf16(a0, bf, acc0[t], 0, 0, 0);
          acc1[t] = __builtin_amdgcn_mfma_f32_16x16x32_bf16(a1, bf, acc1[t], 0, 0, 0);
        }
      }
    }
    {
      const float* eb2l = eb2 + l*128;
      #pragma unroll
      for (int t=0;t<8;t++){
        int col = t*16 + lr; float bv = eb2l[col];
        #pragma unroll
        for (int r=0;r<4;r++){
          sG[0][(qrow+r)*136 + col] = f2bs(acc0[t][r] + dd0[r]*bv);
          sG[1][(qrow+r)*136 + col] = f2bs(acc1[t][r] + dd1[r]*bv);
        }
      }
    }
    // GEMM-B: u = silu([h|aggr] @ nw1 + nb1) -> sG (reuse; aggr fully consumed first)
    #pragma unroll
    for (int t=0;t<8;t++){ acc0[t] = zf; acc1[t] = zf; }
    wave_gemm2(sH[0], sH[1], p_nw1 + (size_t)l*32768,         lane, acc0, acc1);
    wave_gemm2(sG[0], sG[1], p_nw1 + (size_t)l*32768 + 16384, lane, acc0, acc1);
    {
      const float* nb1l = nb1 + l*128;
      #pragma unroll
      for (int t=0;t<8;t++){
        int col = t*16 + lr; float bv = nb1l[col];
        #pragma unroll
        for (int r=0;r<4;r++){
          sG[0][(qrow+r)*136 + col] = f2bs(silu_f(acc0[t][r] + bv));
          sG[1][(qrow+r)*136 + col] = f2bs(silu_f(acc1[t][r] + bv));
        }
      }
    }
    // GEMM-C: h += u @ nw2 + nb2 (register h)
    #pragma unroll
    for (int t=0;t<8;t++){ acc0[t] = zf; acc1[t] = zf; }
    wave_gemm2(sG[0], sG[1], p_nw2 + (size_t)l*16384, lane, acc0, acc1);
    {
      const float* nb2l = nb2 + l*128;
      #pragma unroll
      for (int t=0;t<8;t++){
        int col = t*16 + lr; float bv = nb2l[col];
        #pragma unroll
        for (int r=0;r<4;r++){
          h0a[t][r] += acc0[t][r] + bv;
          h1a[t][r] += acc1[t][r] + bv;
        }
      }
    }
    // restage bf16 h for next layer / head
    #pragma unroll
    for (int t=0;t<8;t++){
      int col = t*16 + lr;
      #pragma unroll
      for (int r=0;r<4;r++){
        sH[0][(qrow+r)*136 + col] = f2bs(h0a[t][r]);
        sH[1][(qrow+r)*136 + col] = f2bs(h1a[t][r]);
      }
    }
  }

  // head: w = silu(h@ow1+ob1)·ow2 + ob2 ; wspin[row] = w * spin[row]
  #pragma unroll
  for (int t=0;t<8;t++){ acc0[t] = zf; acc1[t] = zf; }
  wave_gemm2(sH[0], sH[1], p_ow1, lane, acc0, acc1);
  float p0[4] = {0.f,0.f,0.f,0.f}, p1[4] = {0.f,0.f,0.f,0.f};
  #pragma unroll
  for (int t=0;t<8;t++){
    int col = t*16 + lr;
    float bb = ob1[col], w2 = ow2[col];
    #pragma unroll
    for (int r=0;r<4;r++){
      p0[r] += silu_f(acc0[t][r] + bb)*w2;
      p1[r] += silu_f(acc1[t][r] + bb)*w2;
    }
  }
  #pragma unroll
  for (int m=1;m<16;m<<=1){
    #pragma unroll
    for (int r=0;r<4;r++){
      p0[r] += __shfl_xor(p0[r], m, 64);
      p1[r] += __shfl_xor(p1[r], m, 64);
    }
  }
  if (lr == 0){
    float b = ob2[0];
    #pragma unroll
    for (int r=0;r<4;r++){
      int ra = b0 + qrow + r;
      if (ra < n){
        float wv = p0[r] + b;
        float4 sp = nrec[(size_t)ra*2];
        wspin[ra] = make_float4(wv*sp.x, wv*sp.y, wv*sp.z, 0.f);
      }
      int rb = b1 + qrow + r;
      if (rb < n){
        float wv = p1[r] + b;
        float4 sp = nrec[(size_t)rb*2];
        wspin[rb] = make_float4(wv*sp.x, wv*sp.y, wv*sp.z, 0.f);
      }
    }
  }
}

// ---------------- b_field: quad (16 lanes) per node, single wspin gather ----------------
__global__ __launch_bounds__(256) void k_bfield(const int* __restrict__ srcS,
                                                const float4* __restrict__ wspin,
                                                const int* __restrict__ offs,
                                                const int* __restrict__ deg, float* __restrict__ out, int n){
  int tid = threadIdx.x;
  int lr = tid & 15;
  int i = blockIdx.x*16 + (tid >> 4);
  if (i >= n) return;
  int p0 = offs[i], e = deg[i];
  float ax=0.f, ay=0.f, az=0.f;
  for (int q=lr; q<e; q+=16){
    int s = srcS[p0+q];
    float4 ws = wspin[s];
    ax += ws.x; ay += ws.y; az += ws.z;
  }
  #pragma unroll
  for (int m=1;m<16;m<<=1){
    ax += __shfl_xor(ax, m, 64);
    ay += __shfl_xor(ay, m, 64);
    az += __shfl_xor(az, m, 64);
  }
  if (lr == 0){
    out[(size_t)i*3+0] = ax;
    out[(size_t)i*3+1] = ay;
    out[(size_t)i*3+2] = az;
  }
}

extern "C" void kernel_launch(void* const* d_in, const int* in_sizes, int n_in,
                              void* d_out, int out_size, void* d_ws, size_t ws_size,
                              hipStream_t stream){
  const float* x      = (const float*)d_in[0];
  const int*   ei     = (const int*)  d_in[1];
  const float* eattr  = (const float*)d_in[2];
  const float* in_w   = (const float*)d_in[3];
  const float* in_b   = (const float*)d_in[4];
  const float* ew1    = (const float*)d_in[5];
  const float* eb1    = (const float*)d_in[6];
  const float* ew2    = (const float*)d_in[7];
  const float* eb2    = (const float*)d_in[8];
  const float* nw1    = (const float*)d_in[9];
  const float* nb1    = (const float*)d_in[10];
  const float* nw2    = (const float*)d_in[11];
  const float* nb2    = (const float*)d_in[12];
  const float* ow1    = (const float*)d_in[13];
  const float* ob1    = (const float*)d_in[14];
  const float* ow2    = (const float*)d_in[15];
  const float* ob2    = (const float*)d_in[16];
  float* out = (float*)d_out;

  const int N = in_sizes[0] / 5;
  const int E = in_sizes[1] / 2;
  const int T4 = (N + 3) / 4;          // worst-case class-4 tiles (4 nodes/tile)
  const int T8 = (2*N + 3) / 4;        // worst-case class-8 tiles (2 nodes/tile)

  char* w = (char*)d_ws;
  size_t off = 0;
  auto alloc = [&](size_t bytes)->size_t{
    size_t o = off; off = (off + bytes + 255) & ~(size_t)255; return o;
  };
  size_t o_flag   = alloc(4);
  size_t o_deg    = alloc((size_t)N*4);
  size_t o_offs   = alloc((size_t)N*4);
  size_t o_cursor = alloc((size_t)N*4);
  size_t o_bsum   = alloc(512*4);
  size_t o_nrec   = alloc((size_t)N*32);
  size_t o_wspin  = alloc((size_t)N*16);
  size_t o_A      = alloc((size_t)3*N*128*2);      // 3 layers, bf16 (scaled, lane-major K)
  size_t o_pew2   = alloc((size_t)3*128*128*2);
  size_t o_pnw1   = alloc((size_t)3*256*128*2);
  size_t o_pnw2   = alloc((size_t)3*128*128*2);
  size_t o_pow1   = alloc((size_t)128*128*2);
  size_t o_pew1   = alloc((size_t)3*4096*2);
  size_t o_srcS   = alloc((size_t)E*4);
  size_t o_scE    = alloc((size_t)E*32);
  size_t o_cnt    = alloc(8);
  size_t o_c4     = alloc((size_t)T4*4*16);
  size_t o_c8     = alloc((size_t)T8*4*16);
  if (off > ws_size) return;

  int*    flag   = (int*)   (w + o_flag);
  int*    deg    = (int*)   (w + o_deg);
  int*    offs   = (int*)   (w + o_offs);
  int*    cursor = (int*)   (w + o_cursor);
  int*    bsum   = (int*)   (w + o_bsum);
  float4* nrec   = (float4*)(w + o_nrec);
  float4* wspin  = (float4*)(w + o_wspin);
  ushort* A      = (ushort*)(w + o_A);
  short*  p_ew2  = (short*) (w + o_pew2);
  short*  p_nw1  = (short*) (w + o_pnw1);
  short*  p_nw2  = (short*) (w + o_pnw2);
  short*  p_ow1  = (short*) (w + o_pow1);
  short*  p_ew1  = (short*) (w + o_pew1);
  int*    srcS   = (int*)   (w + o_srcS);
  ushort* scE    = (ushort*)(w + o_scE);
  int*    cnt    = (int*)   (w + o_cnt);
  int4*   c4s    = (int4*)  (w + o_c4);
  int4*   c8s    = (int4*)  (w + o_c8);

  (void)hipMemsetAsync(deg, 0, (size_t)N*4, stream);
  (void)hipMemsetAsync(cnt, 0, 8, stream);
  (void)hipMemsetAsync(c4s, 0xFF, (size_t)T4*4*16, stream);
  (void)hipMemsetAsync(c8s, 0xFF, (size_t)T8*4*16, stream);

  const int nb = (N + 255) / 256;
  const size_t lstride = (size_t)N*128;

  k_detect<<<1, 256, 0, stream>>>(ei, E, flag);
  k_deg<<<(E+255)/256, 256, 0, stream>>>(ei, E, flag, deg);
  // scan1 fused with per-node precompute (nrec)
  k_scan1<<<nb, 256, 0, stream>>>(deg, offs, bsum, x, nrec, N);
  k_scan2<<<1, 512, 0, stream>>>(bsum, nb);
  // scan3 fused with remainder-worklist build
  k_scan3<<<nb, 256, 0, stream>>>(offs, bsum, cursor, deg, cnt, c4s, c8s, N);
  k_scatter<<<(E+255)/256, 256, 0, stream>>>(ei, E, flag, eattr, nrec, cursor, srcS, scE);
  k_pack<<<440, 64, 0, stream>>>(ew2, nw1, nw2, ow1, ew1, eb1,
                                 p_ew2, p_nw1, p_nw2, p_ow1, p_ew1);

  // edge-hidden sums: full groups (+ big tails) per-node, then compact remainders
  k_edge3<<<(N+3)/4, 256, 0, stream>>>(scE, offs, deg, p_ew1, A, N, lstride);
  k_edge_rem<<<(T4+T8+3)/4, 256, 0, stream>>>(scE, cnt, c4s, c8s, p_ew1, A, lstride, T4);

  // all 3 node-update layers + head: 1 wave/block, 2 tiles/wave
  k_layers<<<(N+31)/32, 64, 0, stream>>>(A, lstride, p_ew2, eb2, p_nw1, nb1, p_nw2, nb2,
                                         deg, p_ow1, ob1, ow2, ob2, in_w, in_b,
                                         nrec, wspin, N);

  k_bfield<<<(N+15)/16, 256, 0, stream>>>(srcS, wspin, offs, deg, out, N);
}

// Round 11
// 630.660 us; speedup vs baseline: 1.0965x; 1.0965x over previous
//
#include <hip/hip_runtime.h>
#include <hip/hip_bf16.h>
#include <math.h>

typedef __attribute__((ext_vector_type(8))) short bf16x8;
typedef __attribute__((ext_vector_type(4))) float f32x4;
typedef __attribute__((ext_vector_type(4))) unsigned u32x4;

#define C_NLOG2E -1.4426950408889634f
#define C_NLN2   -0.6931471805599453f

__device__ __forceinline__ float silu_f(float x){
  return x * __builtin_amdgcn_rcpf(1.f + __expf(-x));
}

// scaled-domain silu accumulate: h = -log2e*x (from scaled weights);
// s += h * sigma(x)  ==  s += -log2e * silu(x)   (undone by -ln2 in next GEMM).
// 4 VALU ops: exp2, add, rcp, fmac. PROVEN MINIMAL: all VALU instrs cost the
// same issue slot on this kernel (5-point fit t=126+9.9*ops); both trans-saving
// variants (batched rcp r6, magic rcp r10) added instrs and regressed.
__device__ __forceinline__ void silu_acc(float h, float& s){
  float r = __builtin_amdgcn_rcpf(1.f + __builtin_amdgcn_exp2f(h));
  s = fmaf(h, r, s);
}

// fp32 -> bf16 (round-to-nearest-even, finite inputs)
__device__ __forceinline__ short f2bs(float x){
  unsigned u = __builtin_bit_cast(unsigned, x);
  unsigned r = (u + 0x7fffu + ((u >> 16) & 1u)) >> 16;
  return (short)r;
}
__device__ __forceinline__ float bs2f(ushort u){
  unsigned v = ((unsigned)u) << 16;
  return __builtin_bit_cast(float, v);
}

// pack 2 fp32 -> 2 bf16 in one u32 (RNE), 1 instr; low = first arg
__device__ __forceinline__ unsigned pk2(float a, float b){
  unsigned r;
  asm("v_cvt_pk_bf16_f32 %0, %1, %2" : "=v"(r) : "v"(a), "v"(b));
  return r;
}

// K-permutation for A's hidden dim ONLY (lane-major layout of k_edge3's output):
// A position p holds logical hidden col ((p&7)*16 + (p>>3)); p_ew2 rows permuted to match.
__device__ __forceinline__ int kperm(int k){ return ((k & 7) << 4) | (k >> 3); }

// ---------------- edge-index layout detect (int64 vs int32) + cnt zero ----------------
__global__ void k_detect(const int* __restrict__ ei, int E, int* __restrict__ flag,
                         int* __restrict__ cnt){
  __shared__ int nz;
  if (threadIdx.x==0){ nz = 0; cnt[0] = 0; cnt[1] = 0; }
  __syncthreads();
  int lim = E < 4096 ? E : 4096;
  int c = 0;
  for (int e = threadIdx.x; e < lim; e += blockDim.x)
    if (ei[2*e+1] != 0) c++;
  if (c) atomicAdd(&nz, c);
  __syncthreads();
  if (threadIdx.x==0) *flag = (nz==0) ? 1 : 0;   // 1 => int64 little-endian
}

__global__ __launch_bounds__(256) void k_deg(const int* __restrict__ ei, int E,
                                             const int* __restrict__ flag, int* __restrict__ deg){
  int e = blockIdx.x*blockDim.x + threadIdx.x;
  if (e >= E) return;
  int d = (*flag) ? ei[2*(E+e)] : ei[E+e];
  atomicAdd(&deg[d], 1);
}

// ---------------- scan stage 1 + fused per-node precompute ----------------
__global__ __launch_bounds__(256) void k_scan1(const int* __restrict__ deg, int* __restrict__ offs,
                                               int* __restrict__ bsum,
                                               const float* __restrict__ x, float4* __restrict__ nrec,
                                               int n){
  __shared__ int sh[256];
  int i = blockIdx.x*256 + threadIdx.x;
  int v = (i < n) ? deg[i] : 0;
  sh[threadIdx.x] = v;
  if (i < n){
    float nt0 = x[i*5+0], nt1 = x[i*5+1];
    float sx = x[i*5+2], sy = x[i*5+3], sz = x[i*5+4];
    float nrm = sqrtf(sx*sx + sy*sy + sz*sz);
    float d = fmaxf(nrm, 1e-12f);
    float mx = sx/d, my = sy/d, mz = sz/d;
    float rn = sqrtf(mx*mx + my*my + mz*mz);
    nrec[(size_t)i*2]   = make_float4(mx, my, mz, rn);
    nrec[(size_t)i*2+1] = make_float4(nt0, nt1, 0.f, 0.f);
  }
  __syncthreads();
  for (int off=1; off<256; off<<=1){
    int t = (threadIdx.x >= off) ? sh[threadIdx.x-off] : 0;
    __syncthreads();
    sh[threadIdx.x] += t;
    __syncthreads();
  }
  if (i < n) offs[i] = sh[threadIdx.x] - v;
  if (threadIdx.x == 255) bsum[blockIdx.x] = sh[255];
}

__global__ __launch_bounds__(512) void k_scan2(int* __restrict__ bsum, int nb){
  __shared__ int sh[512];
  int v = (threadIdx.x < nb) ? bsum[threadIdx.x] : 0;
  sh[threadIdx.x] = v;
  __syncthreads();
  for (int off=1; off<512; off<<=1){
    int t = (threadIdx.x >= off) ? sh[threadIdx.x-off] : 0;
    __syncthreads();
    sh[threadIdx.x] += t;
    __syncthreads();
  }
  if (threadIdx.x < nb) bsum[threadIdx.x] = sh[threadIdx.x] - v;
}

// ---------------- scan stage 3 + fused remainder-worklist build ----------------
__global__ __launch_bounds__(256) void k_scan3(int* __restrict__ offs, const int* __restrict__ bsum,
                                               int* __restrict__ cursor,
                                               const int* __restrict__ deg,
                                               int* __restrict__ cnt, int4* __restrict__ c4,
                                               int4* __restrict__ c8, int n){
  int i = blockIdx.x*256 + threadIdx.x;
  if (i >= n) return;
  int o = offs[i] + bsum[i>>8];
  offs[i] = o;
  cursor[i] = o;
  int d = deg[i];
  int r = d & 15;
  if (r == 0 || r >= 9) return;
  int base = o + (d & ~15);
  if (r <= 4){
    int s = atomicAdd(&cnt[0], 1);
    c4[s] = make_int4(i, base, r, 0);
  } else {
    int s = atomicAdd(&cnt[1], 2);         // pair-aligned: node owns quads (q, q+1)
    c8[s]   = make_int4(i, base, 4, 0);
    c8[s+1] = make_int4(i, base+4, r-4, 0);
  }
}

// ---------------- scatter edges into dst-sorted order (32 B bf16 rows) ----------------
// scE row (16 bf16): [|m_i|,|m_j|,mi·mj,mi·u,mj·u,dist,nti0,nti1,ntj0,ntj1, 1.0, 0...]
// Row packed via pk2 (5 instrs instead of ~40).
__global__ __launch_bounds__(256) void k_scatter(const int* __restrict__ ei, int E,
                                                 const int* __restrict__ flag,
                                                 const float* __restrict__ eattr,
                                                 const float4* __restrict__ nrec,
                                                 int* __restrict__ cursor,
                                                 int* __restrict__ srcS, ushort* __restrict__ scE){
  int e = blockIdx.x*blockDim.x + threadIdx.x;
  if (e >= E) return;
  int i64 = *flag;
  int s = i64 ? ei[2*e]       : ei[e];
  int d = i64 ? ei[2*(E+e)]   : ei[E+e];
  float4 ea = *(const float4*)(eattr + (size_t)e*4);
  float4 mi  = nrec[(size_t)d*2];
  float4 nti = nrec[(size_t)d*2+1];
  float4 mj  = nrec[(size_t)s*2];
  float4 ntj = nrec[(size_t)s*2+1];
  u32x4 q0, q1;
  q0[0] = pk2(mi.w, mj.w);
  q0[1] = pk2(mi.x*mj.x + mi.y*mj.y + mi.z*mj.z,
              mi.x*ea.x + mi.y*ea.y + mi.z*ea.z);
  q0[2] = pk2(mj.x*ea.x + mj.y*ea.y + mj.z*ea.z, ea.w);
  q0[3] = pk2(nti.x, nti.y);
  q1[0] = pk2(ntj.x, ntj.y);
  q1[1] = 0x3F80u;   // bf16 1.0 in low slot (bias row), high slot 0
  q1[2] = 0u;
  q1[3] = 0u;
  int pos = atomicAdd(&cursor[d], 1);
  srcS[pos] = s;
  u32x4* dstp = (u32x4*)(scE + (size_t)pos*16);
  dstp[0] = q0;
  dstp[1] = q1;
}

// ---------------- pack weights to MFMA B-fragment-major bf16 ----------------
// p_ew1 scaled by -log2e (incl. bias row). p_ew2 scaled by -ln2 (undoes A's scale)
// AND K-row-permuted by kperm (matches A's lane-major layout). nw1/nw2/ow1 standard.
__global__ __launch_bounds__(64) void k_pack(const float* __restrict__ ew2, const float* __restrict__ nw1,
                                             const float* __restrict__ nw2, const float* __restrict__ ow1,
                                             const float* __restrict__ ew1, const float* __restrict__ eb1,
                                             short* __restrict__ p_ew2, short* __restrict__ p_nw1,
                                             short* __restrict__ p_nw2, short* __restrict__ p_ow1,
                                             short* __restrict__ p_ew1){
  int b = blockIdx.x;
  int L = threadIdx.x;
  if (b >= 416){
    int tile = b - 416;          // 0..23
    int l = tile >> 3, t = tile & 7;
    int col = t*16 + (L & 15);
    int kb  = (L >> 4) << 3;
    __align__(16) short tmp[8];
    #pragma unroll
    for (int e=0;e<8;e++){
      int k = kb + e;
      float v = 0.f;
      if (k < 10)       v = ew1[(size_t)l*1280 + (size_t)k*128 + col];
      else if (k == 10) v = eb1[(size_t)l*128 + col];
      tmp[e] = f2bs(v * C_NLOG2E);
    }
    *(bf16x8*)(p_ew1 + (size_t)l*4096 + t*512 + L*8) = *(bf16x8*)tmp;
    return;
  }
  const float* src; short* dst; int tile;
  float sc = 1.f;
  bool perm = false;
  if (b < 96){        int l = b>>5;              tile = b & 31; src = ew2 + (size_t)l*16384; dst = p_ew2 + (size_t)l*16384; sc = C_NLN2; perm = true; }
  else if (b < 288){  int l = (b-96)>>6;         tile = (b-96) & 63; src = nw1 + (size_t)l*32768; dst = p_nw1 + (size_t)l*32768; }
  else if (b < 384){  int l = (b-288)>>5;        tile = (b-288) & 31; src = nw2 + (size_t)l*16384; dst = p_nw2 + (size_t)l*16384; }
  else {                                          tile = b - 384; src = ow1; dst = p_ow1; }
  int c = tile >> 3, t = tile & 7;
  int kb  = c*32 + ((L>>4)<<3);
  int col = t*16 + (L&15);
  __align__(16) short tmp[8];
  #pragma unroll
  for (int e=0;e<8;e++){
    int k = kb + e;
    int kk = perm ? kperm(k) : k;
    tmp[e] = f2bs(src[(size_t)kk*128 + col] * sc);
  }
  *(bf16x8*)(dst + ((size_t)tile*64 + L)*8) = *(bf16x8*)tmp;
}

// ---------------- edge MLP hidden sums: full 16-groups (+ tails>=9), wave per node ----------------
// A written lane-major: lane lr's 8 sums -> 4 cvt_pk + ONE b128 store.
__global__ __launch_bounds__(256) void k_edge3(
    const ushort* __restrict__ scE,
    const int* __restrict__ offs, const int* __restrict__ deg,
    const short* __restrict__ p_ew1,
    ushort* __restrict__ A, int n, size_t lstride){
  int wv = threadIdx.x >> 6, lane = threadIdx.x & 63;
  int i = blockIdx.x*4 + wv;
  if (i >= n) return;
  int quad = lane >> 4, lr = lane & 15;
  int p0 = __builtin_amdgcn_readfirstlane(offs[i]);
  int dg = __builtin_amdgcn_readfirstlane(deg[i]);
  int r  = dg & 15;
  int gfull = dg & ~15;                         // unmasked full groups
  const f32x4 zf = {0.f,0.f,0.f,0.f};
  const u32x4 z4 = {0u,0u,0u,0u};
  #pragma unroll 1
  for (int l=0; l<3; ++l){
    const short* pB = p_ew1 + (size_t)l*4096 + (size_t)lane*8;
    bf16x8 bfr[8];                                // hoist loop-invariant B-fragments
    #pragma unroll
    for (int t=0;t<8;t++) bfr[t] = *(const bf16x8*)(pB + t*512);
    float s8[8];
    #pragma unroll
    for (int t=0;t<8;t++) s8[t] = 0.f;
    auto body = [&](u32x4 d4){
      bf16x8 af = __builtin_bit_cast(bf16x8, d4);
      #pragma unroll
      for (int t=0;t<8;t++){
        f32x4 acc = __builtin_amdgcn_mfma_f32_16x16x32_bf16(af, bfr[t], zf, 0, 0, 0);
        silu_acc(acc[0], s8[t]);
        silu_acc(acc[1], s8[t]);
        silu_acc(acc[2], s8[t]);
        silu_acc(acc[3], s8[t]);
      }
    };
    for (int g=0; g<gfull; g+=16){                // no per-edge bounds check
      u32x4 d4 = z4;
      if (quad < 2)
        d4 = *(const u32x4*)(scE + ((size_t)(p0+g+lr))*16 + quad*8);
      body(d4);
    }
    if (r >= 9){                                   // single masked tail group
      int e = gfull + lr;
      u32x4 d4 = z4;
      if (quad < 2 && e < dg)
        d4 = *(const u32x4*)(scE + ((size_t)(p0+e))*16 + quad*8);
      body(d4);
    }
    #pragma unroll
    for (int t=0;t<8;t++){
      s8[t] += __shfl_xor(s8[t], 16, 64);
      s8[t] += __shfl_xor(s8[t], 32, 64);
    }
    if (quad == 0){
      u32x4 q;
      q[0] = pk2(s8[0], s8[1]);
      q[1] = pk2(s8[2], s8[3]);
      q[2] = pk2(s8[4], s8[5]);
      q[3] = pk2(s8[6], s8[7]);
      *(u32x4*)(A + lstride*l + (size_t)i*128 + lr*8) = q;
    }
  }
}

// ---------------- remainder tiles: 4 nodes/tile (mode 0) or 2 nodes/tile (mode 1) ----------------
// Bounds-checked against cnt (no sentinel fill needed -> no memsets).
__global__ __launch_bounds__(256) void k_edge_rem(
    const ushort* __restrict__ scE,
    const int* __restrict__ cnt,
    const int4* __restrict__ c4, const int4* __restrict__ c8,
    const short* __restrict__ p_ew1,
    ushort* __restrict__ A, size_t lstride, int T4){
  int wave = threadIdx.x >> 6, lane = threadIdx.x & 63;
  int tw = blockIdx.x*4 + wave;
  const int4* slots;
  int mode, lim;
  if (tw < T4){
    int base = tw*4;
    lim = cnt[0] - base;
    if (lim <= 0) return;
    slots = c4 + base; mode = 0;
  } else {
    int base = (tw - T4)*4;
    lim = cnt[1] - base;
    if (lim <= 0) return;
    slots = c8 + base; mode = 1;
  }
  int lr = lane & 15, quad = lane >> 4;
  int jA = lr >> 2;                         // slot for my A-row
  int jO = quad;                            // slot for my output quad
  int4 sl = make_int4(-1, 0, 0, 0);
  int4 so = make_int4(-1, 0, 0, 0);
  if (jA < lim) sl = slots[jA];
  if (jO < lim) so = slots[jO];
  u32x4 d4 = {0u,0u,0u,0u};
  if (sl.x >= 0 && quad < 2 && (lr & 3) < sl.z)
    d4 = *(const u32x4*)(scE + (size_t)(sl.y + (lr & 3))*16 + quad*8);
  bf16x8 af = __builtin_bit_cast(bf16x8, d4);
  const f32x4 zf = {0.f,0.f,0.f,0.f};
  bool writer = (so.x >= 0) && (mode == 0 || (quad & 1) == 0);
  #pragma unroll 1
  for (int l=0; l<3; ++l){
    const short* pB = p_ew1 + (size_t)l*4096 + (size_t)lane*8;
    float s8[8];
    #pragma unroll
    for (int t=0;t<8;t++){
      bf16x8 bf = *(const bf16x8*)(pB + t*512);
      f32x4 acc = __builtin_amdgcn_mfma_f32_16x16x32_bf16(af, bf, zf, 0, 0, 0);
      float s = 0.f;
      silu_acc(acc[0], s);
      silu_acc(acc[1], s);
      silu_acc(acc[2], s);
      silu_acc(acc[3], s);
      s8[t] = s;
    }
    if (mode == 1){
      #pragma unroll
      for (int t=0;t<8;t++) s8[t] += __shfl_xor(s8[t], 16, 64);
    }
    if (writer){
      ushort* Ar = A + lstride*l + (size_t)so.x*128;
      #pragma unroll
      for (int t=0;t<8;t++){
        int p = lr*8 + t;                   // lane-major position of col t*16+lr
        Ar[p] = (ushort)f2bs(bs2f(Ar[p]) + s8[t]);
      }
    }
  }
}

// ---------------- dual-tile MFMA wave GEMM: 2x (16 rows x 128 cols), shared B-frags ----------------
__device__ __forceinline__ void wave_gemm2(const short* __restrict__ s0, const short* __restrict__ s1,
                                           const short* __restrict__ pw, int lane,
                                           f32x4 acc0[8], f32x4 acc1[8]){
  int lro = (lane & 15)*136 + ((lane >> 4) << 3);
  #pragma unroll
  for (int c=0;c<4;c++){
    bf16x8 a0 = *(const bf16x8*)(s0 + lro + c*32);
    bf16x8 a1 = *(const bf16x8*)(s1 + lro + c*32);
    const short* pB = pw + (size_t)c*4096 + (size_t)lane*8;
    #pragma unroll
    for (int t=0;t<8;t++){
      bf16x8 bf = *(const bf16x8*)(pB + t*512);
      acc0[t] = __builtin_amdgcn_mfma_f32_16x16x32_bf16(a0, bf, acc0[t], 0, 0, 0);
      acc1[t] = __builtin_amdgcn_mfma_f32_16x16x32_bf16(a1, bf, acc1[t], 0, 0, 0);
    }
  }
}

// ---------------- ALL 3 node-update layers + head: 1 wave/block, TWO tiles/wave ----------------
// Known-good r7 version: scalar LDS epilogues, standard sH/sG layout.
// GEMM-A reads A lane-major via permuted p_ew2 (product invariant).
__global__ __launch_bounds__(64,2) void k_layers(
    const ushort* __restrict__ A, size_t lstride,
    const short* __restrict__ p_ew2, const float* __restrict__ eb2,
    const short* __restrict__ p_nw1, const float* __restrict__ nb1,
    const short* __restrict__ p_nw2, const float* __restrict__ nb2,
    const int* __restrict__ deg,
    const short* __restrict__ p_ow1, const float* __restrict__ ob1,
    const float* __restrict__ ow2, const float* __restrict__ ob2,
    const float* __restrict__ inw, const float* __restrict__ inb,
    const float4* __restrict__ nrec, float4* __restrict__ wspin, int n){
  __shared__ __align__(16) short sH[2][2176];
  __shared__ __align__(16) short sG[2][2176];
  int lane = threadIdx.x;
  int lr = lane & 15, quad = lane >> 4, qrow = quad << 2;
  int b0 = blockIdx.x*32;           // tile0 rows b0.., tile1 rows b0+16..
  int b1 = b0 + 16;

  const f32x4 zf = {0.f,0.f,0.f,0.f};
  const bf16x8 zb = {0,0,0,0,0,0,0,0};
  f32x4 h0a[8], h1a[8];
  f32x4 acc0[8], acc1[8];
  bool rv0 = (b0 + lr) < n, rv1 = (b1 + lr) < n;
  float dd0[4], dd1[4];

  // ---- h0 = silu([nt0,nt1,|m|] @ in_w + in_b), both tiles ----
  {
    float nt0a[4], nt1a[4], rna[4], nt0b[4], nt1b[4], rnb[4];
    #pragma unroll
    for (int r=0;r<4;r++){
      int ra = b0 + qrow + r, rb = b1 + qrow + r;
      if (ra < n){
        float4 a = nrec[(size_t)ra*2]; float4 b = nrec[(size_t)ra*2+1];
        nt0a[r]=b.x; nt1a[r]=b.y; rna[r]=a.w; dd0[r]=(float)deg[ra];
      } else { nt0a[r]=0.f; nt1a[r]=0.f; rna[r]=0.f; dd0[r]=0.f; }
      if (rb < n){
        float4 a = nrec[(size_t)rb*2]; float4 b = nrec[(size_t)rb*2+1];
        nt0b[r]=b.x; nt1b[r]=b.y; rnb[r]=a.w; dd1[r]=(float)deg[rb];
      } else { nt0b[r]=0.f; nt1b[r]=0.f; rnb[r]=0.f; dd1[r]=0.f; }
    }
    #pragma unroll
    for (int t=0;t<8;t++){
      int col = t*16 + lr;
      float w0=inw[col], w1=inw[128+col], w2=inw[256+col], bb=inb[col];
      #pragma unroll
      for (int r=0;r<4;r++){
        h0a[t][r] = silu_f(nt0a[r]*w0 + nt1a[r]*w1 + rna[r]*w2 + bb);
        h1a[t][r] = silu_f(nt0b[r]*w0 + nt1b[r]*w1 + rnb[r]*w2 + bb);
      }
    }
    #pragma unroll
    for (int t=0;t<8;t++){
      int col = t*16 + lr;
      #pragma unroll
      for (int r=0;r<4;r++){
        sH[0][(qrow+r)*136 + col] = f2bs(h0a[t][r]);
        sH[1][(qrow+r)*136 + col] = f2bs(h1a[t][r]);
      }
    }
  }

  #pragma unroll 1
  for (int l=0;l<3;++l){
    // GEMM-A: aggr = A @ ew2 + deg*eb2 -> sG ; A-frags straight from global, both tiles
    #pragma unroll
    for (int t=0;t<8;t++){ acc0[t] = zf; acc1[t] = zf; }
    {
      const ushort* gA0 = A + lstride*l + ((size_t)(b0 + lr))*128 + qrow*2;  // k-pos = quad*8
      const ushort* gA1 = A + lstride*l + ((size_t)(b1 + lr))*128 + qrow*2;
      const short* pw = p_ew2 + (size_t)l*16384;
      #pragma unroll
      for (int c=0;c<4;c++){
        bf16x8 a0 = rv0 ? *(const bf16x8*)(gA0 + c*32) : zb;
        bf16x8 a1 = rv1 ? *(const bf16x8*)(gA1 + c*32) : zb;
        const short* pB = pw + (size_t)c*4096 + (size_t)lane*8;
        #pragma unroll
        for (int t=0;t<8;t++){
          bf16x8 bf = *(const bf16x8*)(pB + t*512);
          acc0[t] = __builtin_amdgcn_mfma_f32_16x16x32_bf16(a0, bf, acc0[t], 0, 0, 0);
          acc1[t] = __builtin_amdgcn_mfma_f32_16x16x32_bf16(a1, bf, acc1[t], 0, 0, 0);
        }
      }
    }
    {
      const float* eb2l = eb2 + l*128;
      #pragma unroll
      for (int t=0;t<8;t++){
        int col = t*16 + lr; float bv = eb2l[col];
        #pragma unroll
        for (int r=0;r<4;r++){
          sG[0][(qrow+r)*136 + col] = f2bs(acc0[t][r] + dd0[r]*bv);
          sG[1][(qrow+r)*136 + col] = f2bs(acc1[t][r] + dd1[r]*bv);
        }
      }
    }
    // GEMM-B: u = silu([h|aggr] @ nw1 + nb1) -> sG (reuse; aggr fully consumed first)
    #pragma unroll
    for (int t=0;t<8;t++){ acc0[t] = zf; acc1[t] = zf; }
    wave_gemm2(sH[0], sH[1], p_nw1 + (size_t)l*32768,         lane, acc0, acc1);
    wave_gemm2(sG[0], sG[1], p_nw1 + (size_t)l*32768 + 16384, lane, acc0, acc1);
    {
      const float* nb1l = nb1 + l*128;
      #pragma unroll
      for (int t=0;t<8;t++){
        int col = t*16 + lr; float bv = nb1l[col];
        #pragma unroll
        for (int r=0;r<4;r++){
          sG[0][(qrow+r)*136 + col] = f2bs(silu_f(acc0[t][r] + bv));
          sG[1][(qrow+r)*136 + col] = f2bs(silu_f(acc1[t][r] + bv));
        }
      }
    }
    // GEMM-C: h += u @ nw2 + nb2 (register h)
    #pragma unroll
    for (int t=0;t<8;t++){ acc0[t] = zf; acc1[t] = zf; }
    wave_gemm2(sG[0], sG[1], p_nw2 + (size_t)l*16384, lane, acc0, acc1);
    {
      const float* nb2l = nb2 + l*128;
      #pragma unroll
      for (int t=0;t<8;t++){
        int col = t*16 + lr; float bv = nb2l[col];
        #pragma unroll
        for (int r=0;r<4;r++){
          h0a[t][r] += acc0[t][r] + bv;
          h1a[t][r] += acc1[t][r] + bv;
        }
      }
    }
    // restage bf16 h for next layer / head
    #pragma unroll
    for (int t=0;t<8;t++){
      int col = t*16 + lr;
      #pragma unroll
      for (int r=0;r<4;r++){
        sH[0][(qrow+r)*136 + col] = f2bs(h0a[t][r]);
        sH[1][(qrow+r)*136 + col] = f2bs(h1a[t][r]);
      }
    }
  }

  // head: w = silu(h@ow1+ob1)·ow2 + ob2 ; wspin[row] = w * spin[row]
  #pragma unroll
  for (int t=0;t<8;t++){ acc0[t] = zf; acc1[t] = zf; }
  wave_gemm2(sH[0], sH[1], p_ow1, lane, acc0, acc1);
  float p0[4] = {0.f,0.f,0.f,0.f}, p1[4] = {0.f,0.f,0.f,0.f};
  #pragma unroll
  for (int t=0;t<8;t++){
    int col = t*16 + lr;
    float bb = ob1[col], w2 = ow2[col];
    #pragma unroll
    for (int r=0;r<4;r++){
      p0[r] += silu_f(acc0[t][r] + bb)*w2;
      p1[r] += silu_f(acc1[t][r] + bb)*w2;
    }
  }
  #pragma unroll
  for (int m=1;m<16;m<<=1){
    #pragma unroll
    for (int r=0;r<4;r++){
      p0[r] += __shfl_xor(p0[r], m, 64);
      p1[r] += __shfl_xor(p1[r], m, 64);
    }
  }
  if (lr == 0){
    float b = ob2[0];
    #pragma unroll
    for (int r=0;r<4;r++){
      int ra = b0 + qrow + r;
      if (ra < n){
        float wv = p0[r] + b;
        float4 sp = nrec[(size_t)ra*2];
        wspin[ra] = make_float4(wv*sp.x, wv*sp.y, wv*sp.z, 0.f);
      }
      int rb = b1 + qrow + r;
      if (rb < n){
        float wv = p1[r] + b;
        float4 sp = nrec[(size_t)rb*2];
        wspin[rb] = make_float4(wv*sp.x, wv*sp.y, wv*sp.z, 0.f);
      }
    }
  }
}

// ---------------- b_field: quad (16 lanes) per node, single wspin gather ----------------
__global__ __launch_bounds__(256) void k_bfield(const int* __restrict__ srcS,
                                                const float4* __restrict__ wspin,
                                                const int* __restrict__ offs,
                                                const int* __restrict__ deg, float* __restrict__ out, int n){
  int tid = threadIdx.x;
  int lr = tid & 15;
  int i = blockIdx.x*16 + (tid >> 4);
  if (i >= n) return;
  int p0 = offs[i], e = deg[i];
  float ax=0.f, ay=0.f, az=0.f;
  for (int q=lr; q<e; q+=16){
    int s = srcS[p0+q];
    float4 ws = wspin[s];
    ax += ws.x; ay += ws.y; az += ws.z;
  }
  #pragma unroll
  for (int m=1;m<16;m<<=1){
    ax += __shfl_xor(ax, m, 64);
    ay += __shfl_xor(ay, m, 64);
    az += __shfl_xor(az, m, 64);
  }
  if (lr == 0){
    out[(size_t)i*3+0] = ax;
    out[(size_t)i*3+1] = ay;
    out[(size_t)i*3+2] = az;
  }
}

extern "C" void kernel_launch(void* const* d_in, const int* in_sizes, int n_in,
                              void* d_out, int out_size, void* d_ws, size_t ws_size,
                              hipStream_t stream){
  const float* x      = (const float*)d_in[0];
  const int*   ei     = (const int*)  d_in[1];
  const float* eattr  = (const float*)d_in[2];
  const float* in_w   = (const float*)d_in[3];
  const float* in_b   = (const float*)d_in[4];
  const float* ew1    = (const float*)d_in[5];
  const float* eb1    = (const float*)d_in[6];
  const float* ew2    = (const float*)d_in[7];
  const float* eb2    = (const float*)d_in[8];
  const float* nw1    = (const float*)d_in[9];
  const float* nb1    = (const float*)d_in[10];
  const float* nw2    = (const float*)d_in[11];
  const float* nb2    = (const float*)d_in[12];
  const float* ow1    = (const float*)d_in[13];
  const float* ob1    = (const float*)d_in[14];
  const float* ow2    = (const float*)d_in[15];
  const float* ob2    = (const float*)d_in[16];
  float* out = (float*)d_out;

  const int N = in_sizes[0] / 5;
  const int E = in_sizes[1] / 2;
  const int T4 = (N + 3) / 4;          // worst-case class-4 tiles (4 nodes/tile)
  const int T8 = (2*N + 3) / 4;        // worst-case class-8 tiles (2 nodes/tile)

  char* w = (char*)d_ws;
  size_t off = 0;
  auto alloc = [&](size_t bytes)->size_t{
    size_t o = off; off = (off + bytes + 255) & ~(size_t)255; return o;
  };
  size_t o_flag   = alloc(4);
  size_t o_deg    = alloc((size_t)N*4);
  size_t o_offs   = alloc((size_t)N*4);
  size_t o_cursor = alloc((size_t)N*4);
  size_t o_bsum   = alloc(512*4);
  size_t o_nrec   = alloc((size_t)N*32);
  size_t o_wspin  = alloc((size_t)N*16);
  size_t o_A      = alloc((size_t)3*N*128*2);      // 3 layers, bf16 (scaled, lane-major K)
  size_t o_pew2   = alloc((size_t)3*128*128*2);
  size_t o_pnw1   = alloc((size_t)3*256*128*2);
  size_t o_pnw2   = alloc((size_t)3*128*128*2);
  size_t o_pow1   = alloc((size_t)128*128*2);
  size_t o_pew1   = alloc((size_t)3*4096*2);
  size_t o_srcS   = alloc((size_t)E*4);
  size_t o_scE    = alloc((size_t)E*32);
  size_t o_cnt    = alloc(8);
  size_t o_c4     = alloc((size_t)T4*4*16);
  size_t o_c8     = alloc((size_t)T8*4*16);
  if (off > ws_size) return;

  int*    flag   = (int*)   (w + o_flag);
  int*    deg    = (int*)   (w + o_deg);
  int*    offs   = (int*)   (w + o_offs);
  int*    cursor = (int*)   (w + o_cursor);
  int*    bsum   = (int*)   (w + o_bsum);
  float4* nrec   = (float4*)(w + o_nrec);
  float4* wspin  = (float4*)(w + o_wspin);
  ushort* A      = (ushort*)(w + o_A);
  short*  p_ew2  = (short*) (w + o_pew2);
  short*  p_nw1  = (short*) (w + o_pnw1);
  short*  p_nw2  = (short*) (w + o_pnw2);
  short*  p_ow1  = (short*) (w + o_pow1);
  short*  p_ew1  = (short*) (w + o_pew1);
  int*    srcS   = (int*)   (w + o_srcS);
  ushort* scE    = (ushort*)(w + o_scE);
  int*    cnt    = (int*)   (w + o_cnt);
  int4*   c4s    = (int4*)  (w + o_c4);
  int4*   c8s    = (int4*)  (w + o_c8);

  (void)hipMemsetAsync(deg, 0, (size_t)N*4, stream);

  const int nb = (N + 255) / 256;
  const size_t lstride = (size_t)N*128;

  k_detect<<<1, 256, 0, stream>>>(ei, E, flag, cnt);
  k_deg<<<(E+255)/256, 256, 0, stream>>>(ei, E, flag, deg);
  // scan1 fused with per-node precompute (nrec)
  k_scan1<<<nb, 256, 0, stream>>>(deg, offs, bsum, x, nrec, N);
  k_scan2<<<1, 512, 0, stream>>>(bsum, nb);
  // scan3 fused with remainder-worklist build
  k_scan3<<<nb, 256, 0, stream>>>(offs, bsum, cursor, deg, cnt, c4s, c8s, N);
  k_scatter<<<(E+255)/256, 256, 0, stream>>>(ei, E, flag, eattr, nrec, cursor, srcS, scE);
  k_pack<<<440, 64, 0, stream>>>(ew2, nw1, nw2, ow1, ew1, eb1,
                                 p_ew2, p_nw1, p_nw2, p_ow1, p_ew1);

  // edge-hidden sums: full groups (+ big tails) per-node, then compact remainders
  k_edge3<<<(N+3)/4, 256, 0, stream>>>(scE, offs, deg, p_ew1, A, N, lstride);
  k_edge_rem<<<(T4+T8+3)/4, 256, 0, stream>>>(scE, cnt, c4s, c8s, p_ew1, A, lstride, T4);

  // all 3 node-update layers + head: 1 wave/block, 2 tiles/wave
  k_layers<<<(N+31)/32, 64, 0, stream>>>(A, lstride, p_ew2, eb2, p_nw1, nb1, p_nw2, nb2,
                                         deg, p_ow1, ob1, ow2, ob2, in_w, in_b,
                                         nrec, wspin, N);

  k_bfield<<<(N+15)/16, 256, 0, stream>>>(srcS, wspin, offs, deg, out, N);
}